// Round 9
// baseline (202.824 us; speedup 1.0000x reference)
//
#include <hip/hip_runtime.h>
#include <math.h>

#define NUM_HEADS 16
#define HEAD_DIM 64

typedef __bf16 bf16x8 __attribute__((ext_vector_type(8)));
typedef short shortx4 __attribute__((ext_vector_type(4)));
typedef float floatx4 __attribute__((ext_vector_type(4)));

__device__ __forceinline__ unsigned short f2b(float f) {
  unsigned int u = __float_as_uint(f);
  u += 0x7fffu + ((u >> 16) & 1u);
  return (unsigned short)(u >> 16);
}

__device__ __forceinline__ void async16(const void* g, void* l) {
  __builtin_amdgcn_global_load_lds(
      (const __attribute__((address_space(1))) unsigned int*)g,
      (__attribute__((address_space(3))) unsigned int*)l, 16, 0, 0);
}

__device__ __forceinline__ void cvt4(const float* in, unsigned short* out, int i) {
  float4 v = ((const float4*)in)[i];
  ushort4 o;
  o.x = f2b(v.x); o.y = f2b(v.y); o.z = f2b(v.z); o.w = f2b(v.w);
  ((ushort4*)out)[i] = o;
}

// ------------- prep: all converts + rope table in ONE launch -------------
// z=0: X (4 reps); z=1..4: weights; z=5: rope cos/sin table.
__global__ void prep(const float* __restrict__ x,
                     const float* __restrict__ w0, const float* __restrict__ w1,
                     const float* __restrict__ w2, const float* __restrict__ w3,
                     const int* __restrict__ pos,
                     unsigned short* Xb, unsigned short* o0, unsigned short* o1,
                     unsigned short* o2, unsigned short* o3,
                     float* __restrict__ tab, int xq, int w4, int ntab) {
  int i = blockIdx.x * 256 + threadIdx.x;
  int z = blockIdx.y;
  if (z == 0) {
    if (i < xq) {
#pragma unroll
      for (int rep = 0; rep < 4; ++rep) cvt4(x, Xb, rep * xq + i);
    }
  } else if (z <= 4) {
    if (i < w4) {
      const float* in = (z == 1) ? w0 : (z == 2) ? w1 : (z == 3) ? w2 : w3;
      unsigned short* out = (z == 1) ? o0 : (z == 2) ? o1 : (z == 3) ? o2 : o3;
      cvt4(in, out, i);
    }
  } else {
    if (i < ntab) {
      int fi = i & 31, s = i >> 5;
      float inv = expf(-0.28782313662425575f * (float)fi);
      float ang = (float)pos[s] * inv;
      float sn, cs;
      sincosf(ang, &sn, &cs);
      tab[i * 2] = cs;
      tab[i * 2 + 1] = sn;
    }
  }
}

// ---------------- bf16 GEMM, C = A * B^T (C^T frags) ----------------
// BK=32, single-buffered LDS. MT = M-tile (128 or 64); N-tile fixed 128.
// MT==64 -> 12KB LDS, ~90 VGPR, __launch_bounds__(256,4): 4 resident
// blocks/CU whose MFMA overlaps other blocks' barrier drains (R8-validated
// on the output projection: ~40% faster than MT=128/lb2 at K=1024).
// mfma(b,a): lane holds C[m=lane16][n=g*4+r] -> vector epilogue stores.
// MODE 0: bf16 out; z==0 -> Q (B,H,S,HD) RoPE*1/8; z==1 -> K RoPE;
//         z==2 -> V written TRANSPOSED to (B,H,HD,S).
// MODE 1: fp32 out row-major (M,N).
template <int MODE, int MT>
__global__ __launch_bounds__(256, (MT == 64) ? 4 : 2)
void gemm_bt(const unsigned short* __restrict__ A,
             const unsigned short* __restrict__ B0,
             const unsigned short* __restrict__ B1,
             const unsigned short* __restrict__ B2,
             void* out0v, void* out1v, void* out2v,
             const float* __restrict__ ctab,
             int M, int N, int K, int S) {
  __shared__ unsigned short As[(MT / 16) * 512];
  __shared__ unsigned short Bs[8 * 512];
  const int tid = threadIdx.x;
  const int lane = tid & 63;
  const int w = tid >> 6;
  const int lane16 = lane & 15;
  const int g = lane >> 4;
  const int wm = w >> 1, wn = w & 1;
  const int m0 = blockIdx.y * MT;
  const int n0 = blockIdx.x * 128;
  const unsigned short* Bp = (blockIdx.z == 0) ? B0 : (blockIdx.z == 1 ? B1 : B2);
  constexpr int MTILES = MT / 32;

  const floatx4 vzero = {0.f, 0.f, 0.f, 0.f};
  floatx4 acc[MTILES][4];
#pragma unroll
  for (int i = 0; i < MTILES; i++)
#pragma unroll
    for (int j = 0; j < 4; j++) acc[i][j] = vzero;

  const int ar = lane >> 2;
  const int ac = (lane & 3) * 8;

  for (int k0 = 0; k0 < K; k0 += 32) {
    if constexpr (MT == 128) {
#pragma unroll
      for (int c = 0; c < 2; c++) {
        int chunk = w * 2 + c;
        async16(A  + (size_t)(m0 + chunk * 16 + ar) * K + k0 + ac, As + chunk * 512);
        async16(Bp + (size_t)(n0 + chunk * 16 + ar) * K + k0 + ac, Bs + chunk * 512);
      }
    } else {
      async16(A  + (size_t)(m0 + w * 16 + ar) * K + k0 + ac, As + w * 512);
      async16(Bp + (size_t)(n0 + w * 16 + ar) * K + k0 + ac, Bs + w * 512);
      async16(Bp + (size_t)(n0 + (w + 4) * 16 + ar) * K + k0 + ac, Bs + (w + 4) * 512);
    }
    __syncthreads();
    bf16x8 a[MTILES], b[4];
#pragma unroll
    for (int mt = 0; mt < MTILES; mt++)
      a[mt] = *(const bf16x8*)&As[(wm * (MT / 2) + mt * 16 + lane16) * 32 + g * 8];
#pragma unroll
    for (int nt = 0; nt < 4; nt++)
      b[nt] = *(const bf16x8*)&Bs[(wn * 64 + nt * 16 + lane16) * 32 + g * 8];
#pragma unroll
    for (int mt = 0; mt < MTILES; mt++)
#pragma unroll
      for (int nt = 0; nt < 4; nt++)
        acc[mt][nt] = __builtin_amdgcn_mfma_f32_16x16x32_bf16(b[nt], a[mt], acc[mt][nt], 0, 0, 0);
    __syncthreads();
  }

  if (MODE == 0) {
    if (blockIdx.z < 2) {
      unsigned short* outp = (unsigned short*)((blockIdx.z == 0) ? out0v : out1v);
      const float qs = (blockIdx.z == 0) ? 0.125f : 1.0f;
#pragma unroll
      for (int mt = 0; mt < MTILES; mt++) {
        int m = m0 + wm * (MT / 2) + mt * 16 + lane16;
        int bb = m / S, s = m - bb * S;
        const float* crow = ctab + (size_t)s * 64;
#pragma unroll
        for (int nt = 0; nt < 4; nt++) {
          int n = n0 + wn * 64 + nt * 16 + g * 4;
          int h = n >> 6, dl = n & 63;
          floatx4 v = acc[mt][nt];
          float4 cs = *(const float4*)&crow[dl];
          float r0 = (v[0] * cs.x - v[1] * cs.y) * qs;
          float r1 = (v[0] * cs.y + v[1] * cs.x) * qs;
          float r2 = (v[2] * cs.z - v[3] * cs.w) * qs;
          float r3 = (v[2] * cs.w + v[3] * cs.z) * qs;
          shortx4 st;
          st[0] = (short)f2b(r0); st[1] = (short)f2b(r1);
          st[2] = (short)f2b(r2); st[3] = (short)f2b(r3);
          *(shortx4*)&outp[(((size_t)(bb * NUM_HEADS + h) * S + s) << 6) + dl] = st;
        }
      }
    } else {
      // z==2: V written transposed -> Vt (BH, 64, S).
      unsigned short* outp = (unsigned short*)out2v;
#pragma unroll
      for (int mt = 0; mt < MTILES; mt++) {
        int m = m0 + wm * (MT / 2) + mt * 16 + lane16;
        int bb = m / S, s = m - bb * S;
#pragma unroll
        for (int nt = 0; nt < 4; nt++) {
          int n = n0 + wn * 64 + nt * 16 + g * 4;
          int bh = bb * NUM_HEADS + (n >> 6);
          int dl = n & 63;
          size_t dbase = ((size_t)bh * 64 + dl) * S + s;
#pragma unroll
          for (int r = 0; r < 4; r++)
            outp[dbase + (size_t)r * S] = f2b(acc[mt][nt][r]);
        }
      }
    }
  } else {
    float* outp = (float*)out0v;
#pragma unroll
    for (int mt = 0; mt < MTILES; mt++) {
      int m = m0 + wm * (MT / 2) + mt * 16 + lane16;
#pragma unroll
      for (int nt = 0; nt < 4; nt++) {
        int n = n0 + wn * 64 + nt * 16 + g * 4;
        *(floatx4*)&outp[(size_t)m * N + n] = acc[mt][nt];
      }
    }
  }
}

// ---------------- causal flash attention v4 (champion, verbatim R4) -------
__global__ __launch_bounds__(256, 4)
void flash_attn4(const unsigned short* __restrict__ Q,
                 const unsigned short* __restrict__ Kv,
                 const unsigned short* __restrict__ Vt,
                 unsigned short* __restrict__ Oattn, int S) {
  __shared__ unsigned short Ks[2 * 4096];
  __shared__ unsigned short Vs[2 * 4096];
  const int tid = threadIdx.x;
  const int lane = tid & 63;
  const int w = tid >> 6;
  const int lane16 = lane & 15;
  const int g = lane >> 4;
  const int sw = lane16 & 7;
  const int qt = gridDim.x - 1 - blockIdx.x;   // longest blocks first
  const int bh = blockIdx.y;
  const int b = bh >> 4, h = bh & 15;
  const size_t kbase = (size_t)bh * S * HEAD_DIM;
  const unsigned short* Kbase = Kv + kbase;
  const unsigned short* Vtbase = Vt + (size_t)bh * HEAD_DIM * S;
  const int qrow0 = qt * 64 + w * 16;

  bf16x8 qf0, qf1;
  {
    const unsigned short* qp = Q + kbase + (size_t)(qrow0 + lane16) * HEAD_DIM + g * 8;
    qf0 = *(const bf16x8*)qp;
    qf1 = *(const bf16x8*)(qp + 32);
  }

  const int ci0 = w * 64 + lane;
  const int ci1 = ci0 + 256;
  const int r0 = ci0 >> 3, j0 = (ci0 & 7) ^ (r0 & 7);
  const int r1 = ci1 >> 3, j1 = (ci1 & 7) ^ (r1 & 7);
  const unsigned short* kS0 = Kbase + r0 * HEAD_DIM + j0 * 8;
  const unsigned short* kS1 = Kbase + r1 * HEAD_DIM + j1 * 8;
  const unsigned short* vS0 = Vtbase + (size_t)r0 * S + j0 * 8;
  const unsigned short* vS1 = Vtbase + (size_t)r1 * S + j1 * 8;
  unsigned short* kD0 = Ks + ci0 * 8;
  unsigned short* kD1 = Ks + ci1 * 8;
  unsigned short* vD0 = Vs + ci0 * 8;
  unsigned short* vD1 = Vs + ci1 * 8;

  auto stage = [&](int t, int bi) {
    int koff = t * 4096;
    int voff = t * 64;
    int doff = bi * 4096;
    async16(kS0 + koff, kD0 + doff);
    async16(kS1 + koff, kD1 + doff);
    async16(vS0 + voff, vD0 + doff);
    async16(vS1 + voff, vD1 + doff);
  };

  const floatx4 vzero = {0.f, 0.f, 0.f, 0.f};
  floatx4 oacc[4];
#pragma unroll
  for (int i = 0; i < 4; i++) oacc[i] = vzero;
  float l_i = 0.f;

  stage(0, 0);
  __syncthreads();

  for (int t = 0; t <= qt; ++t) {
    const int bi = t & 1;
    if (t < qt) stage(t + 1, bi ^ 1);
    const unsigned short* Kb_ = Ks + bi * 4096;
    const unsigned short* Vb_ = Vs + bi * 4096;

    floatx4 sc[4];
#pragma unroll
    for (int c = 0; c < 4; ++c) {
      int r = c * 16 + lane16;
      bf16x8 kf0 = *(const bf16x8*)&Kb_[(r * 8 + (g ^ sw)) * 8];
      bf16x8 kf1 = *(const bf16x8*)&Kb_[(r * 8 + ((4 + g) ^ sw)) * 8];
      floatx4 s = vzero;
      s = __builtin_amdgcn_mfma_f32_16x16x32_bf16(kf0, qf0, s, 0, 0, 0);
      s = __builtin_amdgcn_mfma_f32_16x16x32_bf16(kf1, qf1, s, 0, 0, 0);
      sc[c] = s;
    }
    if (t == qt) {
      const int i = qrow0 + lane16;
      const int jb = t * 64;
#pragma unroll
      for (int c = 0; c < 4; ++c)
#pragma unroll
        for (int r = 0; r < 4; ++r)
          if (jb + c * 16 + g * 4 + r > i) sc[c][r] = -INFINITY;
    }
    shortx4 pc[4];
#pragma unroll
    for (int c = 0; c < 4; ++c) {
      float p0 = __expf(sc[c][0]);
      float p1 = __expf(sc[c][1]);
      float p2 = __expf(sc[c][2]);
      float p3 = __expf(sc[c][3]);
      l_i += (p0 + p1) + (p2 + p3);
      union { unsigned int u[2]; shortx4 s4; } pu;
      pu.u[0] = __builtin_amdgcn_perm(__float_as_uint(p1), __float_as_uint(p0), 0x07060302u);
      pu.u[1] = __builtin_amdgcn_perm(__float_as_uint(p3), __float_as_uint(p2), 0x07060302u);
      pc[c] = pu.s4;
    }
#pragma unroll
    for (int nt = 0; nt < 4; ++nt) {
      int rv = nt * 16 + lane16;
#pragma unroll
      for (int c = 0; c < 4; ++c) {
        shortx4 vf = *(const shortx4*)&Vb_[(rv * 8 + ((c * 2 + (g >> 1)) ^ sw)) * 8 + (g & 1) * 4];
        oacc[nt] = __builtin_amdgcn_mfma_f32_16x16x16bf16_1k(vf, pc[c], oacc[nt], 0, 0, 0);
      }
    }
    __syncthreads();
  }

  l_i += __shfl_xor(l_i, 16, 64);
  l_i += __shfl_xor(l_i, 32, 64);
  {
    float inv = 1.0f / l_i;
    int srow = qrow0 + lane16;
    size_t rowb = ((size_t)b * S + srow) * 1024 + h * 64;
#pragma unroll
    for (int nt = 0; nt < 4; ++nt) {
      shortx4 st;
#pragma unroll
      for (int r = 0; r < 4; ++r) st[r] = (short)f2b(oacc[nt][r] * inv);
      *(shortx4*)&Oattn[rowb + nt * 16 + g * 4] = st;
    }
  }
}

// ---------------- launcher ----------------
extern "C" void kernel_launch(void* const* d_in, const int* in_sizes, int n_in,
                              void* d_out, int out_size, void* d_ws, size_t ws_size,
                              hipStream_t stream) {
  const float* x  = (const float*)d_in[0];
  const int*  pos = (const int*)d_in[1];
  const float* wq = (const float*)d_in[2];
  const float* wk = (const float*)d_in[3];
  const float* wv = (const float*)d_in[4];
  const float* wo = (const float*)d_in[5];

  const int D = 1024;
  const int S = in_sizes[1];
  const int M = in_sizes[0] / D;       // B*S
  const int B = M / S;
  const int BH = B * NUM_HEADS;

  char* wsb = (char*)d_ws;
  size_t off = 0;
  auto alloc = [&](size_t bytes) {
    char* p = wsb + off;
    off += (bytes + 255) & ~(size_t)255;
    return p;
  };
  unsigned short* Xb   = (unsigned short*)alloc((size_t)M * D * 2);
  unsigned short* Wqb  = (unsigned short*)alloc((size_t)D * D * 2);
  unsigned short* Wkb  = (unsigned short*)alloc((size_t)D * D * 2);
  unsigned short* Wvb  = (unsigned short*)alloc((size_t)D * D * 2);
  unsigned short* Wob  = (unsigned short*)alloc((size_t)D * D * 2);
  unsigned short* Qb   = (unsigned short*)alloc((size_t)M * D * 2);
  unsigned short* Kb   = (unsigned short*)alloc((size_t)M * D * 2);
  unsigned short* Vtb  = (unsigned short*)alloc((size_t)M * D * 2);  // transposed V
  unsigned short* Attn = (unsigned short*)alloc((size_t)M * D * 2);
  float*          Ctab = (float*)alloc((size_t)S * 32 * 2 * 4);
  (void)ws_size;

  {
    int n4x = M * D / 4;
    int xq = n4x / 4;                 // z=0 threads (4 reps each)
    int w4 = D * D / 4;
    int ntab = S * 32;
    int gx = (w4 + 255) / 256;
    prep<<<dim3(gx, 6), 256, 0, stream>>>(x, wq, wk, wv, wo, pos,
                                          Xb, Wqb, Wkb, Wvb, Wob, Ctab,
                                          xq, w4, ntab);
  }
  // QKV projections, MT=64 (1536 blocks, 4 resident/CU); z==2 writes V^T.
  gemm_bt<0, 64><<<dim3(D / 128, M / 64, 3), 256, 0, stream>>>(
      Xb, Wqb, Wkb, Wvb, Qb, Kb, Vtb, Ctab, M, D, D, S);
  // causal flash attention -> (B*S, D) bf16
  flash_attn4<<<dim3(S / 64, BH), 256, 0, stream>>>(Qb, Kb, Vtb, Attn, S);
  // output projection (MT=64) -> fp32 d_out
  gemm_bt<1, 64><<<dim3(D / 128, M / 64, 1), 256, 0, stream>>>(
      Attn, Wob, Wob, Wob, d_out, d_out, d_out, Ctab, M, D, D, S);
}